// Round 9
// baseline (128.696 us; speedup 1.0000x reference)
//
#include <hip/hip_runtime.h>
#include <cstdint>
#include <cstddef>

#define LSEQ   1024
#define NH     16
#define NX     8
#define CHUNKS 2
#define RPB    512   // rows per moments block

// Moments layout in a 256-slot record (algebra verified rounds 4-8, absmax 2e-3):
//   [0..35]           G upper-tri: G[p][q] at 8p - p(p-1)/2 + (q-p)
//   [36 + ch*16 + e]  C[ch][e] = sum_l x[l,ch]*P[l,e]
//   [163 + m]         S_m = sum_l sin(m*pi*pos), m=1..16   (-> 164..179)
//   [179 + m]         C_m = sum_l cos(m*pi*pos), m=1..16   (-> 180..195)
// Wave split of accumulators (<=52/lane, static indices only — spill-safe):
//   w0: G(36)+S_m(16); w1: C_m(16)+C ch0,1; w2: C ch2,3,4; w3: C ch5,6,7
//
// Codegen rules (rounds 3-8): __launch_bounds__ min-waves = 1; local arrays
// must be statically indexed with plain scalar dataflow (shuffle butterflies
// with cross-element selects demote the array to scratch).

// ===================== K1: per-(batch, half) moment partials =====================
__global__ __launch_bounds__(256, 1)
void moments_kernel(const float* __restrict__ x, const float* __restrict__ pos,
                    float* __restrict__ g_part) {
    __shared__ float sums[256];
    const int tid  = threadIdx.x;
    const int w    = tid >> 6;
    const int lane = tid & 63;
    const int bid  = blockIdx.x;
    const int b    = bid >> 1;
    const int c    = bid & 1;
    const float* xb = x   + ((size_t)b * LSEQ + c * RPB) * NX;
    const float* pb = pos + (size_t)b * LSEQ + c * RPB;

    sums[tid] = 0.f;   // deterministic ws content (slots 196..255 unused)

    float A[52];
    #pragma unroll
    for (int i = 0; i < 52; ++i) A[i] = 0.f;

    for (int i = 0; i < RPB / 64; ++i) {
        const int l = i * 64 + lane;
        const float4 a = *(const float4*)(xb + (size_t)l * 8);
        const float4 cv = *(const float4*)(xb + (size_t)l * 8 + 4);
        const float pv = pb[l];
        const float px[8] = {a.x, a.y, a.z, a.w, cv.x, cv.y, cv.z, cv.w};
        const float s1 = sinpif(pv), c1 = cospif(pv);
        const float c2x = 2.f * c1;

        if (w == 0) {
            #pragma unroll
            for (int p = 0; p < 8; ++p)
                #pragma unroll
                for (int q = p; q < 8; ++q)
                    A[p * 8 - (p * (p - 1)) / 2 + (q - p)] += px[p] * px[q];
            float s = s1, cc = c1, sp = 0.f, cp = 1.f;
            #pragma unroll
            for (int m = 1; m <= 16; ++m) {
                if (m > 1) { const float sn = c2x*s - sp, cn = c2x*cc - cp;
                             sp = s; cp = cc; s = sn; cc = cn; }
                A[35 + m] += s;
            }
        } else if (w == 1) {
            float s = s1, cc = c1, sp = 0.f, cp = 1.f;
            #pragma unroll
            for (int m = 1; m <= 16; ++m) {
                if (m > 1) { const float sn = c2x*s - sp, cn = c2x*cc - cp;
                             sp = s; cp = cc; s = sn; cc = cn; }
                A[m - 1] += cc;
                if (m <= 8) {
                    A[16 + 2*(m-1)] += px[0] * s;  A[16 + 2*m - 1] += px[0] * cc;
                    A[32 + 2*(m-1)] += px[1] * s;  A[32 + 2*m - 1] += px[1] * cc;
                }
            }
        } else if (w == 2) {
            float s = s1, cc = c1, sp = 0.f, cp = 1.f;
            #pragma unroll
            for (int m = 1; m <= 8; ++m) {
                if (m > 1) { const float sn = c2x*s - sp, cn = c2x*cc - cp;
                             sp = s; cp = cc; s = sn; cc = cn; }
                A[ 0 + 2*(m-1)] += px[2] * s;  A[ 0 + 2*m - 1] += px[2] * cc;
                A[16 + 2*(m-1)] += px[3] * s;  A[16 + 2*m - 1] += px[3] * cc;
                A[32 + 2*(m-1)] += px[4] * s;  A[32 + 2*m - 1] += px[4] * cc;
            }
        } else {
            float s = s1, cc = c1, sp = 0.f, cp = 1.f;
            #pragma unroll
            for (int m = 1; m <= 8; ++m) {
                if (m > 1) { const float sn = c2x*s - sp, cn = c2x*cc - cp;
                             sp = s; cp = cc; s = sn; cc = cn; }
                A[ 0 + 2*(m-1)] += px[5] * s;  A[ 0 + 2*m - 1] += px[5] * cc;
                A[16 + 2*(m-1)] += px[6] * s;  A[16 + 2*m - 1] += px[6] * cc;
                A[32 + 2*(m-1)] += px[7] * s;  A[32 + 2*m - 1] += px[7] * cc;
            }
        }
    }

    __syncthreads();   // sums[] zero-init visible
    if (w == 0) {
        #pragma unroll
        for (int j = 0; j < 52; ++j) {
            float v = A[j];
            v += __shfl_xor(v, 1);  v += __shfl_xor(v, 2);  v += __shfl_xor(v, 4);
            v += __shfl_xor(v, 8);  v += __shfl_xor(v, 16); v += __shfl_xor(v, 32);
            if (lane == 0) sums[j < 36 ? j : 128 + j] = v;
        }
    } else if (w == 1) {
        #pragma unroll
        for (int j = 0; j < 48; ++j) {
            float v = A[j];
            v += __shfl_xor(v, 1);  v += __shfl_xor(v, 2);  v += __shfl_xor(v, 4);
            v += __shfl_xor(v, 8);  v += __shfl_xor(v, 16); v += __shfl_xor(v, 32);
            if (lane == 0) sums[j < 16 ? 180 + j : 20 + j] = v;
        }
    } else if (w == 2) {
        #pragma unroll
        for (int j = 0; j < 48; ++j) {
            float v = A[j];
            v += __shfl_xor(v, 1);  v += __shfl_xor(v, 2);  v += __shfl_xor(v, 4);
            v += __shfl_xor(v, 8);  v += __shfl_xor(v, 16); v += __shfl_xor(v, 32);
            if (lane == 0) sums[68 + j] = v;
        }
    } else {
        #pragma unroll
        for (int j = 0; j < 48; ++j) {
            float v = A[j];
            v += __shfl_xor(v, 1);  v += __shfl_xor(v, 2);  v += __shfl_xor(v, 4);
            v += __shfl_xor(v, 8);  v += __shfl_xor(v, 16); v += __shfl_xor(v, 32);
            if (lane == 0) sums[116 + j] = v;
        }
    }
    __syncthreads();
    g_part[(size_t)bid * 256 + tid] = sums[tid];
}

// ============ K2: reduce partials -> score -> softmax -> W_eff -> stream ==========
__global__ __launch_bounds__(256, 1)
void finish_kernel(const float* __restrict__ x,
                   const float* __restrict__ Wq, const float* __restrict__ Wk,
                   const float* __restrict__ Wv, const float* __restrict__ Wo,
                   const float* __restrict__ g_part, float* __restrict__ out) {
    __shared__ float sums[256];
    __shared__ float U_s[128];
    __shared__ float score_s[256];
    __shared__ float attn_s[256];
    __shared__ float M_s[256];
    __shared__ float weff_s[128];

    const int tid = threadIdx.x;
    const int bid = blockIdx.x;
    const int b   = bid >> 1;
    const int c   = bid & 1;
    const float* xb = x + (size_t)b * LSEQ * NX;

    sums[tid] = g_part[(size_t)(b * 2) * 256 + tid]
              + g_part[(size_t)(b * 2 + 1) * 256 + tid];
    __syncthreads();

    // ---------------- score assembly (verified algebra) ---------------------
    if (tid < 128) {                        // U[d][y] = sum_x Wq[d,x]*G[x,y]
        const int d = tid >> 3, y = tid & 7;
        float acc = 0.f;
        #pragma unroll
        for (int xx = 0; xx < 8; ++xx) {
            const int p = xx < y ? xx : y;
            const int q = xx < y ? y : xx;
            acc += Wq[d * 8 + xx] * sums[8 * p - (p * (p - 1)) / 2 + (q - p)];
        }
        U_s[tid] = acc;
    }
    __syncthreads();
    {
        const int d = tid >> 4, e = tid & 15;
        float a1 = 0.f, a2 = 0.f, a3 = 0.f;
        #pragma unroll
        for (int y = 0; y < 8; ++y) a1 += U_s[d * 8 + y] * Wk[e * 8 + y];
        #pragma unroll
        for (int xx = 0; xx < 8; ++xx) {
            a2 += Wq[d * 8 + xx] * sums[36 + xx * 16 + e];
            a3 += Wk[e * 8 + xx] * sums[36 + xx * 16 + d];
        }
        const int fi = (d >> 1) + 1, fj = (e >> 1) + 1;
        const int spd = fi + fj;
        const int smd = fi > fj ? fi - fj : fj - fi;
        const float Smp = sums[163 + spd];
        const float Cmp = sums[179 + spd];
        const float Sms = (smd == 0) ? 0.f : sums[163 + smd];
        const float Cms = (smd == 0) ? (float)LSEQ : sums[179 + smd];
        const bool de = !(d & 1), ee = !(e & 1);
        float Dv;
        if (de && ee)       Dv = 0.5f * (Cms - Cmp);
        else if (de && !ee) Dv = 0.5f * (Smp + (fi >= fj ? 1.f : -1.f) * Sms);
        else if (!de && ee) Dv = 0.5f * (Smp + (fj >= fi ? 1.f : -1.f) * Sms);
        else                Dv = 0.5f * (Cms + Cmp);
        score_s[tid] = (a1 + a2 + a3 + Dv) * 0.03125f;   // 1/sqrt(1024)
    }
    __syncthreads();

    if (tid < 16) {                         // softmax row per thread
        float mx = -1e30f;
        #pragma unroll
        for (int e = 0; e < 16; ++e) mx = fmaxf(mx, score_s[tid * 16 + e]);
        float ex[16], sum = 0.f;
        #pragma unroll
        for (int e = 0; e < 16; ++e) { ex[e] = __expf(score_s[tid * 16 + e] - mx); sum += ex[e]; }
        const float inv = 1.f / sum;
        #pragma unroll
        for (int e = 0; e < 16; ++e) attn_s[tid * 16 + e] = ex[e] * inv;
    }
    __syncthreads();
    {
        const int h = tid >> 4, e = tid & 15;
        float acc = 0.f;
        #pragma unroll
        for (int d = 0; d < 16; ++d) acc += Wo[h * 16 + d] * attn_s[d * 16 + e];
        M_s[tid] = acc;
    }
    __syncthreads();
    if (tid < 128) {
        const int h = tid >> 3, xx = tid & 7;
        float acc = 0.f;
        #pragma unroll
        for (int e = 0; e < 16; ++e) acc += M_s[h * 16 + e] * Wv[e * 8 + xx];
        weff_s[tid] = acc;
    }
    __syncthreads();

    // ------------- epilogue: rows [c*512, c*512+512), 2 rows/thread ---------
    {
        float xr[2][8];
        #pragma unroll
        for (int r = 0; r < 2; ++r) {
            const int l = c * RPB + r * 256 + tid;
            const float4 a = *(const float4*)(xb + (size_t)l * 8);
            const float4 cv = *(const float4*)(xb + (size_t)l * 8 + 4);
            xr[r][0]=a.x; xr[r][1]=a.y; xr[r][2]=a.z; xr[r][3]=a.w;
            xr[r][4]=cv.x; xr[r][5]=cv.y; xr[r][6]=cv.z; xr[r][7]=cv.w;
        }
        float o[2][16];
        #pragma unroll
        for (int h = 0; h < 16; ++h) {
            const float4 wA = *(const float4*)(weff_s + h * 8);
            const float4 wB = *(const float4*)(weff_s + h * 8 + 4);
            #pragma unroll
            for (int r = 0; r < 2; ++r) {
                o[r][h] = xr[r][0]*wA.x + xr[r][1]*wA.y + xr[r][2]*wA.z + xr[r][3]*wA.w
                        + xr[r][4]*wB.x + xr[r][5]*wB.y + xr[r][6]*wB.z + xr[r][7]*wB.w;
            }
        }
        #pragma unroll
        for (int r = 0; r < 2; ++r) {
            const int l = c * RPB + r * 256 + tid;
            const size_t base = ((size_t)b * LSEQ + l) * NH;
            #pragma unroll
            for (int g = 0; g < 4; ++g)
                *(float4*)(out + base + g * 4) =
                    make_float4(o[r][g*4+0], o[r][g*4+1], o[r][g*4+2], o[r][g*4+3]);
        }
    }
}

// ================== fallback: round-8 fused kernel (proven, 101 us) ==============
__global__ __launch_bounds__(256, 1)
void attn_moments4(const float* __restrict__ x, const float* __restrict__ pos,
                   const float* __restrict__ Wq, const float* __restrict__ Wk,
                   const float* __restrict__ Wv, const float* __restrict__ Wo,
                   float* __restrict__ out) {
    __shared__ float sums[256];
    __shared__ float U_s[128];
    __shared__ float score_s[256];
    __shared__ float attn_s[256];
    __shared__ float M_s[256];
    __shared__ float weff_s[128];

    const int tid  = threadIdx.x;
    const int w    = tid >> 6;
    const int lane = tid & 63;
    const int b    = blockIdx.x;
    const float* xb = x   + (size_t)b * LSEQ * NX;
    const float* pb = pos + (size_t)b * LSEQ;

    float A[52];
    #pragma unroll
    for (int i = 0; i < 52; ++i) A[i] = 0.f;

    for (int i = 0; i < 16; ++i) {
        const int l = i * 64 + lane;
        const float4 a = *(const float4*)(xb + (size_t)l * 8);
        const float4 cv = *(const float4*)(xb + (size_t)l * 8 + 4);
        const float pv = pb[l];
        const float px[8] = {a.x, a.y, a.z, a.w, cv.x, cv.y, cv.z, cv.w};
        const float s1 = sinpif(pv), c1 = cospif(pv);
        const float c2x = 2.f * c1;
        if (w == 0) {
            #pragma unroll
            for (int p = 0; p < 8; ++p)
                #pragma unroll
                for (int q = p; q < 8; ++q)
                    A[p * 8 - (p * (p - 1)) / 2 + (q - p)] += px[p] * px[q];
            float s = s1, cc = c1, sp = 0.f, cp = 1.f;
            #pragma unroll
            for (int m = 1; m <= 16; ++m) {
                if (m > 1) { const float sn = c2x*s - sp, cn = c2x*cc - cp;
                             sp = s; cp = cc; s = sn; cc = cn; }
                A[35 + m] += s;
            }
        } else if (w == 1) {
            float s = s1, cc = c1, sp = 0.f, cp = 1.f;
            #pragma unroll
            for (int m = 1; m <= 16; ++m) {
                if (m > 1) { const float sn = c2x*s - sp, cn = c2x*cc - cp;
                             sp = s; cp = cc; s = sn; cc = cn; }
                A[m - 1] += cc;
                if (m <= 8) {
                    A[16 + 2*(m-1)] += px[0] * s;  A[16 + 2*m - 1] += px[0] * cc;
                    A[32 + 2*(m-1)] += px[1] * s;  A[32 + 2*m - 1] += px[1] * cc;
                }
            }
        } else if (w == 2) {
            float s = s1, cc = c1, sp = 0.f, cp = 1.f;
            #pragma unroll
            for (int m = 1; m <= 8; ++m) {
                if (m > 1) { const float sn = c2x*s - sp, cn = c2x*cc - cp;
                             sp = s; cp = cc; s = sn; cc = cn; }
                A[ 0 + 2*(m-1)] += px[2] * s;  A[ 0 + 2*m - 1] += px[2] * cc;
                A[16 + 2*(m-1)] += px[3] * s;  A[16 + 2*m - 1] += px[3] * cc;
                A[32 + 2*(m-1)] += px[4] * s;  A[32 + 2*m - 1] += px[4] * cc;
            }
        } else {
            float s = s1, cc = c1, sp = 0.f, cp = 1.f;
            #pragma unroll
            for (int m = 1; m <= 8; ++m) {
                if (m > 1) { const float sn = c2x*s - sp, cn = c2x*cc - cp;
                             sp = s; cp = cc; s = sn; cc = cn; }
                A[ 0 + 2*(m-1)] += px[5] * s;  A[ 0 + 2*m - 1] += px[5] * cc;
                A[16 + 2*(m-1)] += px[6] * s;  A[16 + 2*m - 1] += px[6] * cc;
                A[32 + 2*(m-1)] += px[7] * s;  A[32 + 2*m - 1] += px[7] * cc;
            }
        }
    }
    if (w == 0) {
        #pragma unroll
        for (int j = 0; j < 52; ++j) {
            float v = A[j];
            v += __shfl_xor(v, 1);  v += __shfl_xor(v, 2);  v += __shfl_xor(v, 4);
            v += __shfl_xor(v, 8);  v += __shfl_xor(v, 16); v += __shfl_xor(v, 32);
            if (lane == 0) sums[j < 36 ? j : 128 + j] = v;
        }
    } else if (w == 1) {
        #pragma unroll
        for (int j = 0; j < 48; ++j) {
            float v = A[j];
            v += __shfl_xor(v, 1);  v += __shfl_xor(v, 2);  v += __shfl_xor(v, 4);
            v += __shfl_xor(v, 8);  v += __shfl_xor(v, 16); v += __shfl_xor(v, 32);
            if (lane == 0) sums[j < 16 ? 180 + j : 20 + j] = v;
        }
    } else if (w == 2) {
        #pragma unroll
        for (int j = 0; j < 48; ++j) {
            float v = A[j];
            v += __shfl_xor(v, 1);  v += __shfl_xor(v, 2);  v += __shfl_xor(v, 4);
            v += __shfl_xor(v, 8);  v += __shfl_xor(v, 16); v += __shfl_xor(v, 32);
            if (lane == 0) sums[68 + j] = v;
        }
    } else {
        #pragma unroll
        for (int j = 0; j < 48; ++j) {
            float v = A[j];
            v += __shfl_xor(v, 1);  v += __shfl_xor(v, 2);  v += __shfl_xor(v, 4);
            v += __shfl_xor(v, 8);  v += __shfl_xor(v, 16); v += __shfl_xor(v, 32);
            if (lane == 0) sums[116 + j] = v;
        }
    }
    __syncthreads();
    if (tid < 128) {
        const int d = tid >> 3, y = tid & 7;
        float acc = 0.f;
        #pragma unroll
        for (int xx = 0; xx < 8; ++xx) {
            const int p = xx < y ? xx : y;
            const int q = xx < y ? y : xx;
            acc += Wq[d * 8 + xx] * sums[8 * p - (p * (p - 1)) / 2 + (q - p)];
        }
        U_s[tid] = acc;
    }
    __syncthreads();
    {
        const int d = tid >> 4, e = tid & 15;
        float a1 = 0.f, a2 = 0.f, a3 = 0.f;
        #pragma unroll
        for (int y = 0; y < 8; ++y) a1 += U_s[d * 8 + y] * Wk[e * 8 + y];
        #pragma unroll
        for (int xx = 0; xx < 8; ++xx) {
            a2 += Wq[d * 8 + xx] * sums[36 + xx * 16 + e];
            a3 += Wk[e * 8 + xx] * sums[36 + xx * 16 + d];
        }
        const int fi = (d >> 1) + 1, fj = (e >> 1) + 1;
        const int spd = fi + fj;
        const int smd = fi > fj ? fi - fj : fj - fi;
        const float Smp = sums[163 + spd];
        const float Cmp = sums[179 + spd];
        const float Sms = (smd == 0) ? 0.f : sums[163 + smd];
        const float Cms = (smd == 0) ? (float)LSEQ : sums[179 + smd];
        const bool de = !(d & 1), ee = !(e & 1);
        float Dv;
        if (de && ee)       Dv = 0.5f * (Cms - Cmp);
        else if (de && !ee) Dv = 0.5f * (Smp + (fi >= fj ? 1.f : -1.f) * Sms);
        else if (!de && ee) Dv = 0.5f * (Smp + (fj >= fi ? 1.f : -1.f) * Sms);
        else                Dv = 0.5f * (Cms + Cmp);
        score_s[tid] = (a1 + a2 + a3 + Dv) * 0.03125f;
    }
    __syncthreads();
    if (tid < 16) {
        float mx = -1e30f;
        #pragma unroll
        for (int e = 0; e < 16; ++e) mx = fmaxf(mx, score_s[tid * 16 + e]);
        float ex[16], sum = 0.f;
        #pragma unroll
        for (int e = 0; e < 16; ++e) { ex[e] = __expf(score_s[tid * 16 + e] - mx); sum += ex[e]; }
        const float inv = 1.f / sum;
        #pragma unroll
        for (int e = 0; e < 16; ++e) attn_s[tid * 16 + e] = ex[e] * inv;
    }
    __syncthreads();
    {
        const int h = tid >> 4, e = tid & 15;
        float acc = 0.f;
        #pragma unroll
        for (int d = 0; d < 16; ++d) acc += Wo[h * 16 + d] * attn_s[d * 16 + e];
        M_s[tid] = acc;
    }
    __syncthreads();
    if (tid < 128) {
        const int h = tid >> 3, xx = tid & 7;
        float acc = 0.f;
        #pragma unroll
        for (int e = 0; e < 16; ++e) acc += M_s[h * 16 + e] * Wv[e * 8 + xx];
        weff_s[tid] = acc;
    }
    __syncthreads();
    #pragma unroll
    for (int pass = 0; pass < 2; ++pass) {
        float xr[2][8];
        #pragma unroll
        for (int r = 0; r < 2; ++r) {
            const int l = pass * 512 + r * 256 + tid;
            const float4 a = *(const float4*)(xb + (size_t)l * 8);
            const float4 cv = *(const float4*)(xb + (size_t)l * 8 + 4);
            xr[r][0]=a.x; xr[r][1]=a.y; xr[r][2]=a.z; xr[r][3]=a.w;
            xr[r][4]=cv.x; xr[r][5]=cv.y; xr[r][6]=cv.z; xr[r][7]=cv.w;
        }
        float o[2][16];
        #pragma unroll
        for (int h = 0; h < 16; ++h) {
            const float4 wA = *(const float4*)(weff_s + h * 8);
            const float4 wB = *(const float4*)(weff_s + h * 8 + 4);
            #pragma unroll
            for (int r = 0; r < 2; ++r) {
                o[r][h] = xr[r][0]*wA.x + xr[r][1]*wA.y + xr[r][2]*wA.z + xr[r][3]*wA.w
                        + xr[r][4]*wB.x + xr[r][5]*wB.y + xr[r][6]*wB.z + xr[r][7]*wB.w;
            }
        }
        #pragma unroll
        for (int r = 0; r < 2; ++r) {
            const int l = pass * 512 + r * 256 + tid;
            const size_t base = ((size_t)b * LSEQ + l) * NH;
            #pragma unroll
            for (int g = 0; g < 4; ++g)
                *(float4*)(out + base + g * 4) =
                    make_float4(o[r][g*4+0], o[r][g*4+1], o[r][g*4+2], o[r][g*4+3]);
        }
    }
}

extern "C" void kernel_launch(void* const* d_in, const int* in_sizes, int n_in,
                              void* d_out, int out_size, void* d_ws, size_t ws_size,
                              hipStream_t stream) {
    const float* x   = (const float*)d_in[0];
    const float* pos = (const float*)d_in[1];
    const float* Wq  = (const float*)d_in[2];
    const float* Wk  = (const float*)d_in[3];
    const float* Wv  = (const float*)d_in[4];
    const float* Wo  = (const float*)d_in[5];
    float* out = (float*)d_out;
    const int B = in_sizes[1] / LSEQ;   // pos has B*L elements

    const size_t ws_needed = (size_t)B * CHUNKS * 256 * sizeof(float);
    if (ws_size >= ws_needed) {
        float* g_part = (float*)d_ws;
        moments_kernel<<<B * CHUNKS, 256, 0, stream>>>(x, pos, g_part);
        finish_kernel<<<B * CHUNKS, 256, 0, stream>>>(x, Wq, Wk, Wv, Wo, g_part, out);
    } else {
        attn_moments4<<<B, 256, 0, stream>>>(x, pos, Wq, Wk, Wv, Wo, out);
    }
}